// Round 2
// baseline (287.313 us; speedup 1.0000x reference)
//
#include <hip/hip_runtime.h>
#include <hip/hip_bf16.h>

#define B_  16
#define C_  256
#define H_  48
#define W_  64
#define ND  21   // displacements per axis
#define HW  (H_ * W_)

typedef __attribute__((ext_vector_type(8))) short bf16x8;
typedef __attribute__((ext_vector_type(4))) float f32x4;

// ---------------------------------------------------------------------------
// Kernel 1: fp32 NCHW -> bf16 NHWC (channels-last) for both inputs.
// grid.x = 2 * B*H*(W/16) = 6144, 256 threads.
// Thread t owns channel c=t and 16 consecutive x: reads its own contiguous
// 64B line (4x float4), writes bf16 coalesced across lanes (consecutive c).
// ---------------------------------------------------------------------------
__global__ __launch_bounds__(256) void transpose_cvt(
    const float* __restrict__ in1, const float* __restrict__ in2,
    unsigned short* __restrict__ o1, unsigned short* __restrict__ o2) {
  int blk = blockIdx.x;
  const float* in = in1;
  unsigned short* op = o1;
  if (blk >= B_ * H_ * (W_ / 16)) {   // second tensor
    blk -= B_ * H_ * (W_ / 16);
    in = in2;
    op = o2;
  }
  int xg = blk & 3;                   // which group of 16 x
  int y  = (blk >> 2) % H_;
  int b  = blk / (4 * H_);
  int c  = threadIdx.x;
  int x0 = xg * 16;

  const float* src = in + (((long)(b * C_ + c) * H_ + y) * W_ + x0);
  float4 v[4];
  v[0] = ((const float4*)src)[0];
  v[1] = ((const float4*)src)[1];
  v[2] = ((const float4*)src)[2];
  v[3] = ((const float4*)src)[3];
  const float* vals = (const float*)v;

  unsigned short* dst = op + (((long)(b * H_ + y) * W_ + x0) * C_ + c);
#pragma unroll
  for (int i = 0; i < 16; i++) {
    unsigned int u = __builtin_bit_cast(unsigned int, vals[i]);
    unsigned int r = (u + 0x7fffu + ((u >> 16) & 1u)) >> 16;  // RTNE to bf16
    dst[i * C_] = (unsigned short)r;
  }
}

// ---------------------------------------------------------------------------
// Kernel 2: correlation via banded GEMM.
// grid.x = B*H = 768, 256 threads (4 waves).
// WG (b,y): A = in1t[b,y] (64x256 bf16) staged once; loop dy: stage
// B = in2t[b,y+dy], compute S = A*B^T (64x64) with 16x16x32 bf16 MFMA,
// write the 21 even diagonals (dx = xp - x), write zeros for OOB dx/dy.
// Output channel ch = dyi*21+dxi has stride H*W (3072 floats).
// LDS: XOR-swizzled granules (16B granule g -> g ^ (row&7)) so the
// 16-lane/row ds_read_b128 pattern is 2-way (free) instead of 16-way.
// ---------------------------------------------------------------------------
__global__ __launch_bounds__(256) void corr_kernel(
    const unsigned short* __restrict__ At, const unsigned short* __restrict__ Bt,
    float* __restrict__ out) {
  __shared__ __align__(16) unsigned short Alds[64 * 256];
  __shared__ __align__(16) unsigned short Blds[64 * 256];

  int blk  = blockIdx.x;
  int y    = blk % H_;
  int b    = blk / H_;
  int t    = threadIdx.x;
  int lane = t & 63;
  int wave = t >> 6;
  int l15  = lane & 15;
  int quad = lane >> 4;

  // ---- stage A (32 KB, contiguous global -> swizzled LDS) ----
  const unsigned short* Asrc = At + (long)(b * H_ + y) * W_ * C_;
#pragma unroll
  for (int k = 0; k < 8; k++) {
    int g = t + 256 * k;            // 16B granule index, 0..2047
    int row = g >> 5, col = g & 31; // row = x, col = k-granule
    uint4 vv = ((const uint4*)Asrc)[g];
    *(uint4*)(Alds + row * 256 + ((col ^ (row & 7)) << 3)) = vv;
  }

  f32x4 acc[4];

  for (int dyi = 0; dyi < ND; dyi++) {
    int y2 = y + 2 * dyi - 20;                                  // block-uniform
    // base of channel (dyi*21 + 0) at row y:
    long outBase = ((long)(b * (ND * ND) + dyi * ND) * H_ + y) * W_;

    if (y2 < 0 || y2 >= H_) {
      // whole dy-slab is zero (zero padding in y): 21 channels x 64 x
      for (int i = t; i < ND * W_; i += 256) {
        int dxi = i >> 6, x = i & 63;
        out[outBase + (long)dxi * HW + x] = 0.0f;
      }
      continue;
    }

    __syncthreads();  // all waves done reading previous B
    const unsigned short* Bsrc = Bt + (long)(b * H_ + y2) * W_ * C_;
#pragma unroll
    for (int k = 0; k < 8; k++) {
      int g = t + 256 * k;
      int row = g >> 5, col = g & 31;
      uint4 vv = ((const uint4*)Bsrc)[g];
      *(uint4*)(Blds + row * 256 + ((col ^ (row & 7)) << 3)) = vv;
    }
    __syncthreads();

#pragma unroll
    for (int nt = 0; nt < 4; nt++) acc[nt] = (f32x4){0.f, 0.f, 0.f, 0.f};

    int am = wave * 16 + l15;       // A row (x) this lane supplies
#pragma unroll
    for (int ks = 0; ks < 8; ks++) {
      int colg = ks * 4 + quad;     // k-granule within row
      bf16x8 a = *(const bf16x8*)(Alds + am * 256 + ((colg ^ (am & 7)) << 3));
#pragma unroll
      for (int nt = 0; nt < 4; nt++) {
        int bn = nt * 16 + l15;     // B row (x') this lane supplies
        bf16x8 bb = *(const bf16x8*)(Blds + bn * 256 + ((colg ^ (bn & 7)) << 3));
        acc[nt] = __builtin_amdgcn_mfma_f32_16x16x32_bf16(a, bb, acc[nt], 0, 0, 0);
      }
    }

    // ---- epilogue: band extraction. C/D layout: col=lane&15, row=quad*4+r ----
    int xbase = wave * 16 + quad * 4;
#pragma unroll
    for (int nt = 0; nt < 4; nt++) {
      int xp = nt * 16 + l15;       // x' = x + dx  (column index n)
#pragma unroll
      for (int r = 0; r < 4; r++) {
        int x = xbase + r;          // row index m
        int dx = xp - x;
        if (dx >= -20 && dx <= 20 && ((dx & 1) == 0)) {
          int dxi = (dx + 20) >> 1;
          out[outBase + (long)dxi * HW + x] = acc[nt][r] * (1.0f / 256.0f);
        }
      }
    }

    // ---- zeros for x+dx out of [0,W): |dx| positions per dxi ----
#pragma unroll
    for (int dxi = 0; dxi < ND; dxi++) {
      int dx = 2 * dxi - 20;
      int cnt = dx < 0 ? -dx : dx;
      if (t < cnt) {
        int x = dx < 0 ? t : (W_ - dx + t);
        out[outBase + (long)dxi * HW + x] = 0.0f;
      }
    }
  }
}

// ---------------------------------------------------------------------------
extern "C" void kernel_launch(void* const* d_in, const int* in_sizes, int n_in,
                              void* d_out, int out_size, void* d_ws, size_t ws_size,
                              hipStream_t stream) {
  (void)in_sizes; (void)n_in; (void)out_size; (void)ws_size;
  const float* in1 = (const float*)d_in[0];
  const float* in2 = (const float*)d_in[1];
  float* out = (float*)d_out;

  unsigned short* o1 = (unsigned short*)d_ws;                       // bf16 [B,H,W,C]
  unsigned short* o2 = o1 + (size_t)B_ * H_ * W_ * C_;              // bf16 [B,H,W,C]

  transpose_cvt<<<2 * B_ * H_ * (W_ / 16), 256, 0, stream>>>(in1, in2, o1, o2);
  corr_kernel<<<B_ * H_, 256, 0, stream>>>(o1, o2, out);
}